// Round 8
// baseline (26923.401 us; speedup 1.0000x reference)
//
#include <hip/hip_runtime.h>
#include <hip/hip_bf16.h>
#include <math.h>

typedef unsigned int uint32;
typedef _Float16 h2_t __attribute__((ext_vector_type(2)));

// Problem constants
static constexpr int NX = 32;    // state dim
static constexpr int NU = 8;     // control dim
static constexpr int NA = 24;    // obs dim
static constexpr int NH = 256;   // hidden
static constexpr int NT = 128;   // time steps
static constexpr int NB = 256;   // batch
static constexpr int NXP = NX + 1;   // padded row (bank-conflict fix)
static constexpr float MINV = 0.01f, MAXV = 1.0f, EPSV = 1e-6f;

// Padded head widths (outputs)
static constexpr int H1O = NX*NX + NX*NU + NX;   // 1312 real
static constexpr int H1P = 1344;                 // padded
static constexpr int H2O = NA*NX + NA;           // 792 real
static constexpr int H2P = 800;                  // padded

// Workspace layout in uint32 units (all 16B aligned)
static constexpr size_t OFF_W1 = 0;
static constexpr size_t OFF_W2 = 4096;
static constexpr size_t OFF_H1 = OFF_W2 + 32768;
static constexpr size_t OFF_H2 = OFF_H1 + 172032;
static constexpr size_t OFF_B1 = OFF_H2 + 102400;
static constexpr size_t OFF_B2 = OFF_B1 + 1344;

// ---------------------------------------------------------------------------
__global__ void pack_half_off(const float* __restrict__ src, uint32* __restrict__ dst,
                              int O, int K, int LDP, int off)
{
    int idx = blockIdx.x * blockDim.x + threadIdx.x;
    int K2 = K >> 1;
    if (idx >= O * K2) return;
    int kk = idx % K2;
    int o  = idx / K2;
    int k  = kk * 2;
    int k8 = k >> 3, q = (k >> 1) & 3;
    _Float16 a = (_Float16)src[o * K + k];
    _Float16 b = (_Float16)src[o * K + k + 1];
    uint32 val = (uint32)__builtin_bit_cast(unsigned short, a)
               | ((uint32)__builtin_bit_cast(unsigned short, b) << 16);
    dst[((size_t)k8 * LDP + off + o) * 4 + q] = val;
}

__global__ void pack_bias3(const float* __restrict__ s0, int n0,
                           const float* __restrict__ s1, int n1,
                           const float* __restrict__ s2, int n2,
                           float* __restrict__ dst)
{
    int i = blockIdx.x * blockDim.x + threadIdx.x;
    if (i < n0) dst[i] = s0[i];
    else if (i < n0 + n1) dst[i] = s1[i - n0];
    else if (i < n0 + n1 + n2) dst[i] = s2[i - n0 - n1];
}

// ---------------------------------------------------------------------------
__device__ __forceinline__ float dot2(uint32 w, uint32 x, float acc)
{
#if __has_builtin(__builtin_amdgcn_fdot2)
    return __builtin_amdgcn_fdot2(__builtin_bit_cast(h2_t, w),
                                  __builtin_bit_cast(h2_t, x), acc, false);
#else
    h2_t a = __builtin_bit_cast(h2_t, w), b = __builtin_bit_cast(h2_t, x);
    return acc + (float)a[0] * (float)b[0] + (float)a[1] * (float)b[1];
#endif
}

__device__ __forceinline__ float dot8(uint4 w, uint4 x, float acc)
{
    acc = dot2(w.x, x.x, acc);
    acc = dot2(w.y, x.y, acc);
    acc = dot2(w.z, x.z, acc);
    acc = dot2(w.w, x.w, acc);
    return acc;
}

__device__ __forceinline__ void tri_decode(int p, int& l, int& i)
{
    int lo = (int)((sqrtf(8.f * (float)p + 1.f) - 1.f) * 0.5f);
    while ((lo + 1) * (lo + 2) / 2 <= p) lo++;
    while (lo * (lo + 1) / 2 > p) lo--;
    l = lo;
    i = p - lo * (lo + 1) / 2;
}

__device__ __forceinline__ float sigm_scaled(float z)
{
    return MINV + (MAXV - MINV) / (1.f + expf(-z));
}

__device__ __forceinline__ unsigned short f2h(float v)
{
    _Float16 h = (_Float16)v;
    return __builtin_bit_cast(unsigned short, h);
}

__device__ __forceinline__ void pack1_to(int tid, float v, uint32* d)
{
    unsigned short us = f2h(v);
    int pi = __shfl_xor((int)us, 1);
    if ((tid & 1) == 0)
        d[tid >> 1] = (uint32)us | ((uint32)pi << 16);
}

// ---------------------------------------------------------------------------
// 1 element/block, 1024 threads, 4 waves/SIMD (VGPR cap 128).
// Weight-stream phases use explicit uint4 w[8] register batches to push
// 8-16 loads in flight per lane (MLP fix); W1 staged in LDS.
__global__ __launch_bounds__(1024, 4) void kf_kernel(
    const float* __restrict__ u, const float* __restrict__ a,
    const uint32* __restrict__ wsu,
    const float* __restrict__ b1, const float* __restrict__ b2,
    const float* __restrict__ alpha_p,
    float* __restrict__ out)
{
    const int tid = threadIdx.x;
    const int b   = blockIdx.x;
    const float alpha = alpha_p[0];

    const uint4* W1h = (const uint4*)(wsu + OFF_W1);
    const uint4* W2h = (const uint4*)(wsu + OFF_W2);
    const uint4* H1h = (const uint4*)(wsu + OFF_H1);
    const uint4* H2h = (const uint4*)(wsu + OFF_H2);
    const float* BH1 = (const float*)(wsu + OFF_B1);
    const float* BH2 = (const float*)(wsu + OFF_B2);

    __shared__ alignas(16) uint4  s_W1[4 * NH];        // 16 KB, L2->LDS once
    __shared__ alignas(16) uint32 s_h1h[NH / 2];
    __shared__ alignas(16) uint32 s_h2h[NH / 2];
    __shared__ alignas(16) uint32 s_qmh[NX / 2];
    __shared__ alignas(16) uint32 s_pmh[NX / 2];
    __shared__ float s_part[4][NH];
    __shared__ float s_Am[NX * NXP];
    __shared__ float s_Bm[NX * NU];
    __shared__ float s_nx[NX];
    __shared__ float s_C[NA * NXP];
    __shared__ float s_na[NA];
    __shared__ float s_qm[NX], s_qc[NX * NXP];
    __shared__ float s_pm[NX], s_pc[NX * NXP];
    __shared__ float s_T2[NX * NXP];
    __shared__ float s_T1[NA * NXP];
    __shared__ float s_S[NA * NA];
    __shared__ float s_Y[NA * NX];
    __shared__ float s_innov[NA];
    __shared__ float s_a[NA], s_u[NU];

    const size_t pmO = 0;
    const size_t pcO = (size_t)NT * NB * NX;
    const size_t qmO = pcO + (size_t)NT * NB * NX * NX;
    const size_t qcO = qmO + (size_t)NT * NB * NX;

    // Hoisted triangular index maps (constant over t)
    int iT = 0, lT = 0;
    if (tid < 528) tri_decode(tid, lT, iT);
    int iS = 0, lS = 0;
    if (tid < 300) tri_decode(tid, lS, iS);

    // Stage W1 into LDS (4*256 uint4 == 1024 lanes, one each)
    s_W1[tid] = W1h[tid];

    for (int t = 0; t < NT; ++t) {
        const size_t mIdx = (size_t)t * NB + b;

        if (t == 0) {
            if (tid < NX) s_pm[tid] = 0.f;
            if (tid < NX / 2) s_pmh[tid] = 0u;
            {
                int i = tid >> 5, l = tid & 31;
                s_pc[i * NXP + l] = (i == l) ? 1.f : 0.f;
            }
            __syncthreads();
        } else {
            // ===== A1: lanes<256: W1@qm (LDS) ; lanes>=256: store qm/qc[t-1] =====
            if (tid < NH) {
                const uint4* xh = (const uint4*)s_qmh;
                float acc = b1[tid];
                #pragma unroll
                for (int k8 = 0; k8 < 4; k8++)
                    acc = dot8(s_W1[k8 * NH + tid], xh[k8], acc);
                pack1_to(tid, fmaxf(acc, 0.f), s_h1h);
            } else {
                const size_t mPrev = (size_t)(t - 1) * NB + b;
                for (int s = tid - 256; s < NX + NX * NX; s += 768) {
                    if (s < NX)
                        __builtin_nontemporal_store(s_qm[s], out + qmO + mPrev * NX + s);
                    else {
                        int o = s - NX, i = o >> 5, l = o & 31;
                        __builtin_nontemporal_store(s_qc[i * NXP + l],
                                                    out + qcO + mPrev * NX * NX + o);
                    }
                }
                if (tid >= 1016)
                    s_u[tid - 1016] = u[((size_t)(t - 1) * NB + b) * NU + (tid - 1016)];
            }
            __syncthreads();

            // ===== A2: trunk-W2 split-K x4 — batched 8 loads in flight =====
            {
                int o = tid & 255, g = tid >> 8;
                const uint4* xh = (const uint4*)s_h1h;
                uint4 w[8];
                #pragma unroll
                for (int r = 0; r < 8; r++)
                    w[r] = W2h[(g * 8 + r) * NH + o];
                float acc = 0.f;
                #pragma unroll
                for (int r = 0; r < 8; r++)
                    acc = dot8(w[r], xh[g * 8 + r], acc);
                s_part[g][o] = acc;
            }
            __syncthreads();

            // ===== A3: h2 reduce + relu + pack =====
            if (tid < NH) {
                float v = fmaxf(s_part[0][tid] + s_part[1][tid] +
                                s_part[2][tid] + s_part[3][tid] + b2[tid], 0.f);
                pack1_to(tid, v, s_h2h);
            }
            __syncthreads();

            // ===== A4: head1 — batched: 8 (or 16) loads in flight per lane =====
            {
                const uint4* xh = (const uint4*)s_h2h;
                int o0 = tid, o1 = tid + 1024;
                bool has1 = (o1 < H1O);
                float a0 = BH1[o0];
                float a1 = has1 ? BH1[o1] : 0.f;
                #pragma unroll
                for (int kb = 0; kb < 4; kb++) {
                    uint4 w0[8], w1[8];
                    #pragma unroll
                    for (int r = 0; r < 8; r++)
                        w0[r] = H1h[(kb * 8 + r) * H1P + o0];
                    if (has1) {
                        #pragma unroll
                        for (int r = 0; r < 8; r++)
                            w1[r] = H1h[(kb * 8 + r) * H1P + o1];
                    }
                    #pragma unroll
                    for (int r = 0; r < 8; r++) {
                        uint4 x = xh[kb * 8 + r];
                        a0 = dot8(w0[r], x, a0);
                        if (has1) a1 = dot8(w1[r], x, a1);
                    }
                }
                {
                    int i = o0 >> 5, l = o0 & 31;
                    s_Am[i * NXP + l] = ((i == l) ? 1.f : 0.f) + alpha * a0;
                }
                if (has1) {
                    if (o1 < NX * NX + NX * NU) s_Bm[o1 - NX * NX] = a1;
                    else s_nx[o1 - (NX * NX + NX * NU)] = sigm_scaled(a1);
                }
            }
            __syncthreads();

            // ===== A5: T2 = Am@qc (1/lane) ; pm = Am@qm + Bm@u =====
            {
                int i = tid >> 5, l = tid & 31;
                float acc = 0.f;
                #pragma unroll
                for (int j = 0; j < NX; j++)
                    acc = fmaf(s_Am[i * NXP + j], s_qc[j * NXP + l], acc);
                s_T2[i * NXP + l] = acc;
            }
            if (tid < NX) {
                float acc = 0.f;
                #pragma unroll
                for (int j = 0; j < NX; j++) acc = fmaf(s_Am[tid * NXP + j], s_qm[j], acc);
                #pragma unroll
                for (int j = 0; j < NU; j++) acc = fmaf(s_Bm[tid * NU + j], s_u[j], acc);
                s_pm[tid] = acc;
                pack1_to(tid, acc, s_pmh);
            }
            __syncthreads();

            // ===== A6: pc = psd(T2 @ Am^T + diag(nx)) — 1/lane =====
            if (tid < 528) {
                int i = iT, l = lT;
                float a_il = 0.f, a_li = 0.f;
                #pragma unroll
                for (int j = 0; j < NX; j++) {
                    a_il = fmaf(s_T2[i * NXP + j], s_Am[l * NXP + j], a_il);
                    a_li = fmaf(s_T2[l * NXP + j], s_Am[i * NXP + j], a_li);
                }
                if (i == l) {
                    s_pc[i * NXP + i] = a_il + s_nx[i] + EPSV;
                } else {
                    float v = 0.5f * (a_il + a_li);
                    s_pc[i * NXP + l] = v;
                    s_pc[l * NXP + i] = v;
                }
            }
            __syncthreads();
        }

        // ===== B1: lanes<256: W1@pm (LDS) ; lanes>=256: store pm/pc[t] =====
        if (tid < NH) {
            const uint4* xh = (const uint4*)s_pmh;
            float acc = b1[tid];
            #pragma unroll
            for (int k8 = 0; k8 < 4; k8++)
                acc = dot8(s_W1[k8 * NH + tid], xh[k8], acc);
            pack1_to(tid, fmaxf(acc, 0.f), s_h1h);
        } else {
            for (int s = tid - 256; s < NX + NX * NX; s += 768) {
                if (s < NX)
                    __builtin_nontemporal_store(s_pm[s], out + pmO + mIdx * NX + s);
                else {
                    int o = s - NX, i = o >> 5, l = o & 31;
                    __builtin_nontemporal_store(s_pc[i * NXP + l],
                                                out + pcO + mIdx * NX * NX + o);
                }
            }
            if (tid >= 1000)
                s_a[tid - 1000] = a[mIdx * NA + (tid - 1000)];
        }
        __syncthreads();

        // ===== B2: trunk-W2 split-K x4 — batched =====
        {
            int o = tid & 255, g = tid >> 8;
            const uint4* xh = (const uint4*)s_h1h;
            uint4 w[8];
            #pragma unroll
            for (int r = 0; r < 8; r++)
                w[r] = W2h[(g * 8 + r) * NH + o];
            float acc = 0.f;
            #pragma unroll
            for (int r = 0; r < 8; r++)
                acc = dot8(w[r], xh[g * 8 + r], acc);
            s_part[g][o] = acc;
        }
        __syncthreads();

        // ===== B3: h2 reduce + relu + pack =====
        if (tid < NH) {
            float v = fmaxf(s_part[0][tid] + s_part[1][tid] +
                            s_part[2][tid] + s_part[3][tid] + b2[tid], 0.f);
            pack1_to(tid, v, s_h2h);
        }
        __syncthreads();

        // ===== B4: head2 (C | na) — batched 8 loads in flight =====
        if (tid < H2P) {
            const uint4* xh = (const uint4*)s_h2h;
            float acc = BH2[tid];
            #pragma unroll
            for (int kb = 0; kb < 4; kb++) {
                uint4 w[8];
                #pragma unroll
                for (int r = 0; r < 8; r++)
                    w[r] = H2h[(kb * 8 + r) * H2P + tid];
                #pragma unroll
                for (int r = 0; r < 8; r++)
                    acc = dot8(w[r], xh[kb * 8 + r], acc);
            }
            if (tid < NA * NX) {
                int i = tid >> 5, l = tid & 31;
                s_C[i * NXP + l] = acc;
            } else if (tid < H2O) {
                s_na[tid - NA * NX] = sigm_scaled(acc);
            }
        }
        __syncthreads();

        // ===== B5: T1 = C@pc (1/lane) ; innov = a - C@pm =====
        if (tid < NA * NX) {
            int i = tid >> 5, l = tid & 31;
            float acc = 0.f;
            #pragma unroll
            for (int k = 0; k < NX; k++)
                acc = fmaf(s_C[i * NXP + k], s_pc[k * NXP + l], acc);
            s_T1[i * NXP + l] = acc;
        }
        if (tid >= 1000) {
            int i = tid - 1000;
            float acc = s_a[i];
            #pragma unroll
            for (int j = 0; j < NX; j++)
                acc = fmaf(-s_C[i * NXP + j], s_pm[j], acc);
            s_innov[i] = acc;
        }
        __syncthreads();

        // ===== B6: S = T1 @ C^T + diag(na) — 1/lane =====
        if (tid < 300) {
            float acc = 0.f;
            #pragma unroll
            for (int j = 0; j < NX; j++)
                acc = fmaf(s_T1[iS * NXP + j], s_C[lS * NXP + j], acc);
            if (iS == lS) acc += s_na[iS];
            s_S[iS * NA + lS] = acc;
            s_S[lS * NA + iS] = acc;
        }
        __syncthreads();

        // ===== B7: single-wave register Gauss-Jordan: Y = S^-1 T1 =====
        if (tid < 64) {
            const int j = tid;
            float r[NA];
            #pragma unroll
            for (int i = 0; i < NA; i++) {
                float v = 0.f;
                if (j < NA) v = s_S[i * NA + j];
                else if (j < NA + NX) v = s_T1[i * NXP + (j - NA)];
                r[i] = v;
            }
            #pragma unroll
            for (int k = 0; k < NA; k++) {
                float piv = __shfl(r[k], k);
                float ip = 1.0f / piv;
                r[k] *= ip;
                #pragma unroll
                for (int i = 0; i < NA; i++) {
                    if (i == k) continue;
                    float f = __shfl(r[i], k);
                    r[i] = fmaf(-f, r[k], r[i]);
                }
            }
            if (j >= NA && j < NA + NX) {
                #pragma unroll
                for (int i = 0; i < NA; i++) s_Y[i * NX + (j - NA)] = r[i];
            }
        }
        __syncthreads();

        // ===== B8: qm = pm + Y^T innov ; qc = psd(pc - Y^T T1) — 1/lane =====
        if (tid < NX) {
            float acc = s_pm[tid];
            #pragma unroll
            for (int i = 0; i < NA; i++)
                acc = fmaf(s_Y[i * NX + tid], s_innov[i], acc);
            s_qm[tid] = acc;
            pack1_to(tid, acc, s_qmh);
        }
        if (tid < 528) {
            int i = iT, l = lT;
            float t_il = 0.f, t_li = 0.f;
            #pragma unroll
            for (int q = 0; q < NA; q++) {
                t_il = fmaf(s_Y[q * NX + i], s_T1[q * NXP + l], t_il);
                t_li = fmaf(s_Y[q * NX + l], s_T1[q * NXP + i], t_li);
            }
            if (i == l) {
                s_qc[i * NXP + i] = s_pc[i * NXP + i] - t_il + EPSV;
            } else {
                float v = 0.5f * ((s_pc[i * NXP + l] - t_il) + (s_pc[l * NXP + i] - t_li));
                s_qc[i * NXP + l] = v;
                s_qc[l * NXP + i] = v;
            }
        }
        __syncthreads();
    }

    // Epilogue: store final qm/qc (t = NT-1), coalesced
    {
        const size_t mLast = (size_t)(NT - 1) * NB + b;
        for (int s = tid; s < NX + NX * NX; s += 1024) {
            if (s < NX)
                __builtin_nontemporal_store(s_qm[s], out + qmO + mLast * NX + s);
            else {
                int o = s - NX, i = o >> 5, l = o & 31;
                __builtin_nontemporal_store(s_qc[i * NXP + l],
                                            out + qcO + mLast * NX * NX + o);
            }
        }
    }
}

// ---------------------------------------------------------------------------
extern "C" void kernel_launch(void* const* d_in, const int* in_sizes, int n_in,
                              void* d_out, int out_size, void* d_ws, size_t ws_size,
                              hipStream_t stream)
{
    const float* u    = (const float*)d_in[0];
    const float* a    = (const float*)d_in[1];
    const float* W1   = (const float*)d_in[2];
    const float* b1   = (const float*)d_in[3];
    const float* W2   = (const float*)d_in[4];
    const float* b2   = (const float*)d_in[5];
    const float* WA   = (const float*)d_in[6];
    const float* bA   = (const float*)d_in[7];
    const float* WB   = (const float*)d_in[8];
    const float* bB   = (const float*)d_in[9];
    const float* WC   = (const float*)d_in[10];
    const float* bC   = (const float*)d_in[11];
    const float* Wnx  = (const float*)d_in[12];
    const float* bnx  = (const float*)d_in[13];
    const float* Wna  = (const float*)d_in[14];
    const float* bna  = (const float*)d_in[15];
    const float* alph = (const float*)d_in[16];

    uint32* wsu = (uint32*)d_ws;
    float* out = (float*)d_out;

    auto pk = [&](const float* src, int O, int K, size_t dst_off, int LDP, int off) {
        int n = O * (K / 2);
        pack_half_off<<<(n + 255) / 256, 256, 0, stream>>>(src, wsu + dst_off, O, K, LDP, off);
    };
    pk(W1,  NH,      NX, OFF_W1, NH,  0);
    pk(W2,  NH,      NH, OFF_W2, NH,  0);
    pk(WA,  NX * NX, NH, OFF_H1, H1P, 0);
    pk(WB,  NX * NU, NH, OFF_H1, H1P, NX * NX);
    pk(Wnx, NX,      NH, OFF_H1, H1P, NX * NX + NX * NU);
    pk(WC,  NA * NX, NH, OFF_H2, H2P, 0);
    pk(Wna, NA,      NH, OFF_H2, H2P, NA * NX);

    pack_bias3<<<(H1O + 255) / 256, 256, 0, stream>>>(bA, NX * NX, bB, NX * NU, bnx, NX,
                                                      (float*)(wsu + OFF_B1));
    pack_bias3<<<(H2O + 255) / 256, 256, 0, stream>>>(bC, NA * NX, bna, NA, nullptr, 0,
                                                      (float*)(wsu + OFF_B2));

    kf_kernel<<<NB, 1024, 0, stream>>>(u, a, wsu, b1, b2, alph, out);
}

// Round 9
// 6026.568 us; speedup vs baseline: 4.4675x; 4.4675x over previous
//
#include <hip/hip_runtime.h>
#include <hip/hip_bf16.h>
#include <math.h>

typedef unsigned int uint32;
typedef _Float16 h2_t __attribute__((ext_vector_type(2)));
typedef float f32x2 __attribute__((ext_vector_type(2)));

// Problem constants
static constexpr int NX = 32;    // state dim
static constexpr int NU = 8;     // control dim
static constexpr int NA = 24;    // obs dim
static constexpr int NH = 256;   // hidden
static constexpr int NT = 128;   // time steps
static constexpr int NB = 256;   // batch
static constexpr int NXP = NX + 1;   // padded row (bank-conflict fix)
static constexpr float MINV = 0.01f, MAXV = 1.0f, EPSV = 1e-6f;

// Padded head widths (outputs)
static constexpr int H1O = NX*NX + NX*NU + NX;   // 1312 real
static constexpr int H1P = 1344;                 // padded
static constexpr int H2O = NA*NX + NA;           // 792 real
static constexpr int H2P = 800;                  // padded

// Workspace layout in uint32 units (all 16B aligned)
// W1 fp16 [k8][o] uint4 rows; W2/H1/H2 fp8 [k16][o] uint4 (16 weights each)
static constexpr size_t OFF_W1   = 0;                       // 4096 u32 (16 KB)
static constexpr size_t OFF_W2F8 = 4096;                    // 16384 u32 (64 KB)
static constexpr size_t OFF_H1F8 = OFF_W2F8 + 16384;        // 86016 u32
static constexpr size_t OFF_H2F8 = OFF_H1F8 + 86016;        // 51200 u32
static constexpr size_t OFF_B1   = OFF_H2F8 + 51200;        // 1344 floats
static constexpr size_t OFF_B2   = OFF_B1 + 1344;           // 800 floats

// ---------------------------------------------------------------------------
__global__ void pack_half_off(const float* __restrict__ src, uint32* __restrict__ dst,
                              int O, int K, int LDP, int off)
{
    int idx = blockIdx.x * blockDim.x + threadIdx.x;
    int K2 = K >> 1;
    if (idx >= O * K2) return;
    int kk = idx % K2;
    int o  = idx / K2;
    int k  = kk * 2;
    int k8 = k >> 3, q = (k >> 1) & 3;
    _Float16 a = (_Float16)src[o * K + k];
    _Float16 b = (_Float16)src[o * K + k + 1];
    uint32 val = (uint32)__builtin_bit_cast(unsigned short, a)
               | ((uint32)__builtin_bit_cast(unsigned short, b) << 16);
    dst[((size_t)k8 * LDP + off + o) * 4 + q] = val;
}

// OCP e4m3fn encode (RNE-ish, saturating; NaN-free inputs assumed)
__device__ unsigned int enc_e4m3(float x)
{
    unsigned int s = (x < 0.f) ? 0x80u : 0u;
    float av = fabsf(x);
    if (av > 448.f) av = 448.f;
    if (av < 0.015625f) {                      // subnormal: m * 2^-9
        int q = (int)rintf(av * 512.f);
        if (q > 8) q = 8;
        if (q == 8) return s | 0x08;           // rounds up to 2^-6
        return s | (unsigned)q;
    }
    int ef; float mm = frexpf(av, &ef);        // av = mm*2^ef, mm in [0.5,1)
    int E = ef - 1 + 7;
    int q = (int)rintf((mm * 2.f - 1.f) * 8.f);
    if (q == 8) { E += 1; q = 0; }
    if (E > 15 || (E == 15 && q > 6)) { E = 15; q = 6; }   // max 448
    return s | ((unsigned)E << 3) | (unsigned)q;
}

// Pack fp32 [O][K] -> fp8 e4m3, 16 weights per uint4 at [(k16*LDP + off + o)]
__global__ void pack_fp8_off(const float* __restrict__ src, uint32* __restrict__ dst,
                             int O, int K, int LDP, int off)
{
    int idx = blockIdx.x * blockDim.x + threadIdx.x;
    int K16 = K >> 4;
    if (idx >= O * K16) return;
    int k16 = idx % K16;
    int o   = idx / K16;
    uint32 w[4] = {0u, 0u, 0u, 0u};
    for (int j = 0; j < 16; j++) {
        unsigned int b = enc_e4m3(src[o * K + k16 * 16 + j]);
        w[j >> 2] |= b << (8 * (j & 3));
    }
    size_t base = ((size_t)k16 * LDP + off + o) * 4;
    dst[base + 0] = w[0]; dst[base + 1] = w[1];
    dst[base + 2] = w[2]; dst[base + 3] = w[3];
}

__global__ void pack_bias3(const float* __restrict__ s0, int n0,
                           const float* __restrict__ s1, int n1,
                           const float* __restrict__ s2, int n2,
                           float* __restrict__ dst)
{
    int i = blockIdx.x * blockDim.x + threadIdx.x;
    if (i < n0) dst[i] = s0[i];
    else if (i < n0 + n1) dst[i] = s1[i - n0];
    else if (i < n0 + n1 + n2) dst[i] = s2[i - n0 - n1];
}

// ---------------------------------------------------------------------------
__device__ __forceinline__ float dot2(uint32 w, uint32 x, float acc)
{
#if __has_builtin(__builtin_amdgcn_fdot2)
    return __builtin_amdgcn_fdot2(__builtin_bit_cast(h2_t, w),
                                  __builtin_bit_cast(h2_t, x), acc, false);
#else
    h2_t a = __builtin_bit_cast(h2_t, w), b = __builtin_bit_cast(h2_t, x);
    return acc + (float)a[0] * (float)b[0] + (float)a[1] * (float)b[1];
#endif
}

__device__ __forceinline__ float dot8(uint4 w, uint4 x, float acc)
{
    acc = dot2(w.x, x.x, acc);
    acc = dot2(w.y, x.y, acc);
    acc = dot2(w.z, x.z, acc);
    acc = dot2(w.w, x.w, acc);
    return acc;
}

#if !__has_builtin(__builtin_amdgcn_cvt_pk_f32_fp8)
__device__ __forceinline__ float fp8_dec1(unsigned int b)
{
    int s = (b >> 7) & 1, e = (b >> 3) & 15, m = b & 7;
    float v = e ? ldexpf(1.f + m * 0.125f, e - 7) : ldexpf(m * 0.125f, -6);
    return s ? -v : v;
}
#endif

// 16 fp8 weights (uint4) dotted with 16 floats at xb (16B-aligned LDS)
__device__ __forceinline__ float dot16_fp8(uint4 w, const float* __restrict__ xb,
                                           float acc)
{
#if __has_builtin(__builtin_amdgcn_cvt_pk_f32_fp8)
    const float4* xv = (const float4*)xb;
    uint32 wq[4] = {w.x, w.y, w.z, w.w};
    #pragma unroll
    for (int q = 0; q < 4; q++) {
        f32x2 lo = __builtin_amdgcn_cvt_pk_f32_fp8(wq[q], false);
        f32x2 hi = __builtin_amdgcn_cvt_pk_f32_fp8(wq[q], true);
        float4 x = xv[q];
        acc = fmaf(lo.x, x.x, acc);
        acc = fmaf(lo.y, x.y, acc);
        acc = fmaf(hi.x, x.z, acc);
        acc = fmaf(hi.y, x.w, acc);
    }
    return acc;
#else
    uint32 wq[4] = {w.x, w.y, w.z, w.w};
    #pragma unroll
    for (int q = 0; q < 4; q++)
        #pragma unroll
        for (int bth = 0; bth < 4; bth++)
            acc = fmaf(fp8_dec1((wq[q] >> (8 * bth)) & 0xff), xb[q * 4 + bth], acc);
    return acc;
#endif
}

__device__ __forceinline__ void tri_decode(int p, int& l, int& i)
{
    int lo = (int)((sqrtf(8.f * (float)p + 1.f) - 1.f) * 0.5f);
    while ((lo + 1) * (lo + 2) / 2 <= p) lo++;
    while (lo * (lo + 1) / 2 > p) lo--;
    l = lo;
    i = p - lo * (lo + 1) / 2;
}

__device__ __forceinline__ float sigm_scaled(float z)
{
    return MINV + (MAXV - MINV) / (1.f + expf(-z));
}

__device__ __forceinline__ unsigned short f2h(float v)
{
    _Float16 h = (_Float16)v;
    return __builtin_bit_cast(unsigned short, h);
}

__device__ __forceinline__ void pack1_to(int tid, float v, uint32* d)
{
    unsigned short us = f2h(v);
    int pi = __shfl_xor((int)us, 1);
    if ((tid & 1) == 0)
        d[tid >> 1] = (uint32)us | ((uint32)pi << 16);
}

// ---------------------------------------------------------------------------
// R7 skeleton: 1 elem/block, 1024 threads. fp8 heads+W2 (56% fewer stream
// bytes), W1 staged in LDS, hidden vectors as LDS floats (wave-broadcast).
__global__ __launch_bounds__(1024, 4) void kf_kernel(
    const float* __restrict__ u, const float* __restrict__ a,
    const uint32* __restrict__ wsu,
    const float* __restrict__ b1, const float* __restrict__ b2,
    const float* __restrict__ alpha_p,
    float* __restrict__ out)
{
    const int tid = threadIdx.x;
    const int b   = blockIdx.x;
    const float alpha = alpha_p[0];

    const uint4* W1h  = (const uint4*)(wsu + OFF_W1);
    const uint4* W2f8 = (const uint4*)(wsu + OFF_W2F8);
    const uint4* H1f8 = (const uint4*)(wsu + OFF_H1F8);
    const uint4* H2f8 = (const uint4*)(wsu + OFF_H2F8);
    const float* BH1  = (const float*)(wsu + OFF_B1);
    const float* BH2  = (const float*)(wsu + OFF_B2);

    __shared__ alignas(16) uint4  s_W1[4 * NH];     // 16 KB
    __shared__ alignas(16) float  s_h1f[NH];
    __shared__ alignas(16) float  s_h2f[NH];
    __shared__ alignas(16) uint32 s_qmh[NX / 2];
    __shared__ alignas(16) uint32 s_pmh[NX / 2];
    __shared__ float s_part[4][NH];
    __shared__ float s_Am[NX * NXP];
    __shared__ float s_Bm[NX * NU];
    __shared__ float s_nx[NX];
    __shared__ float s_C[NA * NXP];
    __shared__ float s_na[NA];
    __shared__ float s_qm[NX], s_qc[NX * NXP];
    __shared__ float s_pm[NX], s_pc[NX * NXP];
    __shared__ float s_T2[NX * NXP];
    __shared__ float s_T1[NA * NXP];
    __shared__ float s_S[NA * NA];
    __shared__ float s_Y[NA * NX];
    __shared__ float s_innov[NA];
    __shared__ float s_a[NA], s_u[NU];

    const size_t pmO = 0;
    const size_t pcO = (size_t)NT * NB * NX;
    const size_t qmO = pcO + (size_t)NT * NB * NX * NX;
    const size_t qcO = qmO + (size_t)NT * NB * NX;

    // Hoisted triangular index maps (constant over t)
    int iT = 0, lT = 0;
    if (tid < 528) tri_decode(tid, lT, iT);
    int iS = 0, lS = 0;
    if (tid < 300) tri_decode(tid, lS, iS);

    // Stage W1 into LDS (1024 uint4, one per lane)
    s_W1[tid] = W1h[tid];

    for (int t = 0; t < NT; ++t) {
        const size_t mIdx = (size_t)t * NB + b;

        if (t == 0) {
            if (tid < NX) s_pm[tid] = 0.f;
            if (tid < NX / 2) s_pmh[tid] = 0u;
            {
                int i = tid >> 5, l = tid & 31;
                s_pc[i * NXP + l] = (i == l) ? 1.f : 0.f;
            }
            __syncthreads();
        } else {
            // ===== A1: lanes<256: W1@qm (LDS fp16) ; others: store qm/qc[t-1] =====
            if (tid < NH) {
                const uint4* xh = (const uint4*)s_qmh;
                float acc = b1[tid];
                #pragma unroll
                for (int k8 = 0; k8 < 4; k8++)
                    acc = dot8(s_W1[k8 * NH + tid], xh[k8], acc);
                s_h1f[tid] = fmaxf(acc, 0.f);
            } else {
                const size_t mPrev = (size_t)(t - 1) * NB + b;
                for (int s = tid - 256; s < NX + NX * NX; s += 768) {
                    if (s < NX)
                        __builtin_nontemporal_store(s_qm[s], out + qmO + mPrev * NX + s);
                    else {
                        int o = s - NX, i = o >> 5, l = o & 31;
                        __builtin_nontemporal_store(s_qc[i * NXP + l],
                                                    out + qcO + mPrev * NX * NX + o);
                    }
                }
                if (tid >= 1016)
                    s_u[tid - 1016] = u[((size_t)(t - 1) * NB + b) * NU + (tid - 1016)];
            }
            __syncthreads();

            // ===== A2: trunk-W2 fp8, split-K x4 =====
            {
                int o = tid & 255, g = tid >> 8;
                float acc = 0.f;
                #pragma unroll
                for (int r = 0; r < 4; r++) {
                    int k16 = g * 4 + r;
                    acc = dot16_fp8(W2f8[k16 * NH + o], s_h1f + k16 * 16, acc);
                }
                s_part[g][o] = acc;
            }
            __syncthreads();

            // ===== A3: h2 reduce + relu =====
            if (tid < NH) {
                s_h2f[tid] = fmaxf(s_part[0][tid] + s_part[1][tid] +
                                   s_part[2][tid] + s_part[3][tid] + b2[tid], 0.f);
            }
            __syncthreads();

            // ===== A4: head1 fp8 (Am | Bm | nx) =====
            {
                int o0 = tid, o1 = tid + 1024;
                bool has1 = (o1 < H1O);
                float a0 = BH1[o0];
                float a1 = has1 ? BH1[o1] : 0.f;
                #pragma unroll 4
                for (int k16 = 0; k16 < 16; k16++) {
                    const float* xb = s_h2f + k16 * 16;
                    a0 = dot16_fp8(H1f8[k16 * H1P + o0], xb, a0);
                    if (has1) a1 = dot16_fp8(H1f8[k16 * H1P + o1], xb, a1);
                }
                {
                    int i = o0 >> 5, l = o0 & 31;
                    s_Am[i * NXP + l] = ((i == l) ? 1.f : 0.f) + alpha * a0;
                }
                if (has1) {
                    if (o1 < NX * NX + NX * NU) s_Bm[o1 - NX * NX] = a1;
                    else s_nx[o1 - (NX * NX + NX * NU)] = sigm_scaled(a1);
                }
            }
            __syncthreads();

            // ===== A5: T2 = Am@qc (1/lane) ; pm = Am@qm + Bm@u =====
            {
                int i = tid >> 5, l = tid & 31;
                float acc = 0.f;
                #pragma unroll
                for (int j = 0; j < NX; j++)
                    acc = fmaf(s_Am[i * NXP + j], s_qc[j * NXP + l], acc);
                s_T2[i * NXP + l] = acc;
            }
            if (tid < NX) {
                float acc = 0.f;
                #pragma unroll
                for (int j = 0; j < NX; j++) acc = fmaf(s_Am[tid * NXP + j], s_qm[j], acc);
                #pragma unroll
                for (int j = 0; j < NU; j++) acc = fmaf(s_Bm[tid * NU + j], s_u[j], acc);
                s_pm[tid] = acc;
                pack1_to(tid, acc, s_pmh);
            }
            __syncthreads();

            // ===== A6: pc = psd(T2 @ Am^T + diag(nx)) — 1/lane =====
            if (tid < 528) {
                int i = iT, l = lT;
                float a_il = 0.f, a_li = 0.f;
                #pragma unroll
                for (int j = 0; j < NX; j++) {
                    a_il = fmaf(s_T2[i * NXP + j], s_Am[l * NXP + j], a_il);
                    a_li = fmaf(s_T2[l * NXP + j], s_Am[i * NXP + j], a_li);
                }
                if (i == l) {
                    s_pc[i * NXP + i] = a_il + s_nx[i] + EPSV;
                } else {
                    float v = 0.5f * (a_il + a_li);
                    s_pc[i * NXP + l] = v;
                    s_pc[l * NXP + i] = v;
                }
            }
            __syncthreads();
        }

        // ===== B1: lanes<256: W1@pm (LDS fp16) ; others: store pm/pc[t] =====
        if (tid < NH) {
            const uint4* xh = (const uint4*)s_pmh;
            float acc = b1[tid];
            #pragma unroll
            for (int k8 = 0; k8 < 4; k8++)
                acc = dot8(s_W1[k8 * NH + tid], xh[k8], acc);
            s_h1f[tid] = fmaxf(acc, 0.f);
        } else {
            for (int s = tid - 256; s < NX + NX * NX; s += 768) {
                if (s < NX)
                    __builtin_nontemporal_store(s_pm[s], out + pmO + mIdx * NX + s);
                else {
                    int o = s - NX, i = o >> 5, l = o & 31;
                    __builtin_nontemporal_store(s_pc[i * NXP + l],
                                                out + pcO + mIdx * NX * NX + o);
                }
            }
            if (tid >= 1000)
                s_a[tid - 1000] = a[mIdx * NA + (tid - 1000)];
        }
        __syncthreads();

        // ===== B2: trunk-W2 fp8, split-K x4 =====
        {
            int o = tid & 255, g = tid >> 8;
            float acc = 0.f;
            #pragma unroll
            for (int r = 0; r < 4; r++) {
                int k16 = g * 4 + r;
                acc = dot16_fp8(W2f8[k16 * NH + o], s_h1f + k16 * 16, acc);
            }
            s_part[g][o] = acc;
        }
        __syncthreads();

        // ===== B3: h2 reduce + relu =====
        if (tid < NH) {
            s_h2f[tid] = fmaxf(s_part[0][tid] + s_part[1][tid] +
                               s_part[2][tid] + s_part[3][tid] + b2[tid], 0.f);
        }
        __syncthreads();

        // ===== B4: head2 fp8 (C | na), 1/lane =====
        if (tid < H2P) {
            float acc = BH2[tid];
            #pragma unroll 4
            for (int k16 = 0; k16 < 16; k16++)
                acc = dot16_fp8(H2f8[k16 * H2P + tid], s_h2f + k16 * 16, acc);
            if (tid < NA * NX) {
                int i = tid >> 5, l = tid & 31;
                s_C[i * NXP + l] = acc;
            } else if (tid < H2O) {
                s_na[tid - NA * NX] = sigm_scaled(acc);
            }
        }
        __syncthreads();

        // ===== B5: T1 = C@pc (1/lane) ; innov = a - C@pm =====
        if (tid < NA * NX) {
            int i = tid >> 5, l = tid & 31;
            float acc = 0.f;
            #pragma unroll
            for (int k = 0; k < NX; k++)
                acc = fmaf(s_C[i * NXP + k], s_pc[k * NXP + l], acc);
            s_T1[i * NXP + l] = acc;
        }
        if (tid >= 1000) {
            int i = tid - 1000;
            float acc = s_a[i];
            #pragma unroll
            for (int j = 0; j < NX; j++)
                acc = fmaf(-s_C[i * NXP + j], s_pm[j], acc);
            s_innov[i] = acc;
        }
        __syncthreads();

        // ===== B6: S = T1 @ C^T + diag(na) — 1/lane =====
        if (tid < 300) {
            float acc = 0.f;
            #pragma unroll
            for (int j = 0; j < NX; j++)
                acc = fmaf(s_T1[iS * NXP + j], s_C[lS * NXP + j], acc);
            if (iS == lS) acc += s_na[iS];
            s_S[iS * NA + lS] = acc;
            s_S[lS * NA + iS] = acc;
        }
        __syncthreads();

        // ===== B7: single-wave register Gauss-Jordan: Y = S^-1 T1 =====
        if (tid < 64) {
            const int j = tid;
            float r[NA];
            #pragma unroll
            for (int i = 0; i < NA; i++) {
                float v = 0.f;
                if (j < NA) v = s_S[i * NA + j];
                else if (j < NA + NX) v = s_T1[i * NXP + (j - NA)];
                r[i] = v;
            }
            #pragma unroll
            for (int k = 0; k < NA; k++) {
                float piv = __shfl(r[k], k);
                float ip = 1.0f / piv;
                r[k] *= ip;
                #pragma unroll
                for (int i = 0; i < NA; i++) {
                    if (i == k) continue;
                    float f = __shfl(r[i], k);
                    r[i] = fmaf(-f, r[k], r[i]);
                }
            }
            if (j >= NA && j < NA + NX) {
                #pragma unroll
                for (int i = 0; i < NA; i++) s_Y[i * NX + (j - NA)] = r[i];
            }
        }
        __syncthreads();

        // ===== B8: qm = pm + Y^T innov ; qc = psd(pc - Y^T T1) — 1/lane =====
        if (tid < NX) {
            float acc = s_pm[tid];
            #pragma unroll
            for (int i = 0; i < NA; i++)
                acc = fmaf(s_Y[i * NX + tid], s_innov[i], acc);
            s_qm[tid] = acc;
            pack1_to(tid, acc, s_qmh);
        }
        if (tid < 528) {
            int i = iT, l = lT;
            float t_il = 0.f, t_li = 0.f;
            #pragma unroll
            for (int q = 0; q < NA; q++) {
                t_il = fmaf(s_Y[q * NX + i], s_T1[q * NXP + l], t_il);
                t_li = fmaf(s_Y[q * NX + l], s_T1[q * NXP + i], t_li);
            }
            if (i == l) {
                s_qc[i * NXP + i] = s_pc[i * NXP + i] - t_il + EPSV;
            } else {
                float v = 0.5f * ((s_pc[i * NXP + l] - t_il) + (s_pc[l * NXP + i] - t_li));
                s_qc[i * NXP + l] = v;
                s_qc[l * NXP + i] = v;
            }
        }
        __syncthreads();
    }

    // Epilogue: store final qm/qc (t = NT-1), coalesced
    {
        const size_t mLast = (size_t)(NT - 1) * NB + b;
        for (int s = tid; s < NX + NX * NX; s += 1024) {
            if (s < NX)
                __builtin_nontemporal_store(s_qm[s], out + qmO + mLast * NX + s);
            else {
                int o = s - NX, i = o >> 5, l = o & 31;
                __builtin_nontemporal_store(s_qc[i * NXP + l],
                                            out + qcO + mLast * NX * NX + o);
            }
        }
    }
}

// ---------------------------------------------------------------------------
extern "C" void kernel_launch(void* const* d_in, const int* in_sizes, int n_in,
                              void* d_out, int out_size, void* d_ws, size_t ws_size,
                              hipStream_t stream)
{
    const float* u    = (const float*)d_in[0];
    const float* a    = (const float*)d_in[1];
    const float* W1   = (const float*)d_in[2];
    const float* b1   = (const float*)d_in[3];
    const float* W2   = (const float*)d_in[4];
    const float* b2   = (const float*)d_in[5];
    const float* WA   = (const float*)d_in[6];
    const float* bA   = (const float*)d_in[7];
    const float* WB   = (const float*)d_in[8];
    const float* bB   = (const float*)d_in[9];
    const float* WC   = (const float*)d_in[10];
    const float* bC   = (const float*)d_in[11];
    const float* Wnx  = (const float*)d_in[12];
    const float* bnx  = (const float*)d_in[13];
    const float* Wna  = (const float*)d_in[14];
    const float* bna  = (const float*)d_in[15];
    const float* alph = (const float*)d_in[16];

    uint32* wsu = (uint32*)d_ws;
    float* out = (float*)d_out;

    // W1 stays fp16 (staged to LDS in-kernel)
    {
        int n = NH * (NX / 2);
        pack_half_off<<<(n + 255) / 256, 256, 0, stream>>>(W1, wsu + OFF_W1, NH, NX, NH, 0);
    }
    // fp8 packs
    auto pk8 = [&](const float* src, int O, int K, size_t dst_off, int LDP, int off) {
        int n = O * (K / 16);
        pack_fp8_off<<<(n + 255) / 256, 256, 0, stream>>>(src, wsu + dst_off, O, K, LDP, off);
    };
    pk8(W2,  NH,      NH, OFF_W2F8, NH,  0);
    pk8(WA,  NX * NX, NH, OFF_H1F8, H1P, 0);
    pk8(WB,  NX * NU, NH, OFF_H1F8, H1P, NX * NX);
    pk8(Wnx, NX,      NH, OFF_H1F8, H1P, NX * NX + NX * NU);
    pk8(WC,  NA * NX, NH, OFF_H2F8, H2P, 0);
    pk8(Wna, NA,      NH, OFF_H2F8, H2P, NA * NX);

    pack_bias3<<<(H1O + 255) / 256, 256, 0, stream>>>(bA, NX * NX, bB, NX * NU, bnx, NX,
                                                      (float*)(wsu + OFF_B1));
    pack_bias3<<<(H2O + 255) / 256, 256, 0, stream>>>(bC, NA * NX, bna, NA, nullptr, 0,
                                                      (float*)(wsu + OFF_B2));

    kf_kernel<<<NB, 1024, 0, stream>>>(u, a, wsu, b1, b2, alph, out);
}

// Round 10
// 5303.909 us; speedup vs baseline: 5.0761x; 1.1363x over previous
//
#include <hip/hip_runtime.h>
#include <hip/hip_bf16.h>
#include <math.h>

typedef unsigned int uint32;
typedef _Float16 h2_t __attribute__((ext_vector_type(2)));

// Problem constants
static constexpr int NX = 32;    // state dim
static constexpr int NU = 8;     // control dim
static constexpr int NA = 24;    // obs dim
static constexpr int NH = 256;   // hidden
static constexpr int NT = 128;   // time steps
static constexpr int NB = 256;   // batch
static constexpr int NXP = NX + 1;   // padded row (bank-conflict fix)
static constexpr float MINV = 0.01f, MAXV = 1.0f, EPSV = 1e-6f;

// Padded head widths (outputs)
static constexpr int H1O = NX*NX + NX*NU + NX;   // 1312 real
static constexpr int H1P = 1344;                 // padded
static constexpr int H2O = NA*NX + NA;           // 792 real
static constexpr int H2P = 800;                  // padded

// Workspace layout in uint32 units (all 16B aligned)
// W1 fp16 [k8][o] uint4; W2/H1/H2 fp8 e4m3 [k16][o] uint4 (16 weights)
static constexpr size_t OFF_W1   = 0;                       // 4096 u32
static constexpr size_t OFF_W2F8 = 4096;                    // 16384 u32
static constexpr size_t OFF_H1F8 = OFF_W2F8 + 16384;        // 86016 u32
static constexpr size_t OFF_H2F8 = OFF_H1F8 + 86016;        // 51200 u32
static constexpr size_t OFF_B1   = OFF_H2F8 + 51200;        // 1344 floats
static constexpr size_t OFF_B2   = OFF_B1 + 1344;           // 800 floats

// ---------------------------------------------------------------------------
__global__ void pack_half_off(const float* __restrict__ src, uint32* __restrict__ dst,
                              int O, int K, int LDP, int off)
{
    int idx = blockIdx.x * blockDim.x + threadIdx.x;
    int K2 = K >> 1;
    if (idx >= O * K2) return;
    int kk = idx % K2;
    int o  = idx / K2;
    int k  = kk * 2;
    int k8 = k >> 3, q = (k >> 1) & 3;
    _Float16 a = (_Float16)src[o * K + k];
    _Float16 b = (_Float16)src[o * K + k + 1];
    uint32 val = (uint32)__builtin_bit_cast(unsigned short, a)
               | ((uint32)__builtin_bit_cast(unsigned short, b) << 16);
    dst[((size_t)k8 * LDP + off + o) * 4 + q] = val;
}

// OCP e4m3fn encode (RNE-ish, saturating)
__device__ unsigned int enc_e4m3(float x)
{
    unsigned int s = (x < 0.f) ? 0x80u : 0u;
    float av = fabsf(x);
    if (av > 448.f) av = 448.f;
    if (av < 0.015625f) {
        int q = (int)rintf(av * 512.f);
        if (q > 8) q = 8;
        if (q == 8) return s | 0x08;
        return s | (unsigned)q;
    }
    int ef; float mm = frexpf(av, &ef);
    int E = ef - 1 + 7;
    int q = (int)rintf((mm * 2.f - 1.f) * 8.f);
    if (q == 8) { E += 1; q = 0; }
    if (E > 15 || (E == 15 && q > 6)) { E = 15; q = 6; }
    return s | ((unsigned)E << 3) | (unsigned)q;
}

// Pack fp32 [O][K] -> fp8 e4m3, 16 weights per uint4 at [(k16*LDP + off + o)]
__global__ void pack_fp8_off(const float* __restrict__ src, uint32* __restrict__ dst,
                             int O, int K, int LDP, int off)
{
    int idx = blockIdx.x * blockDim.x + threadIdx.x;
    int K16 = K >> 4;
    if (idx >= O * K16) return;
    int k16 = idx % K16;
    int o   = idx / K16;
    uint32 w[4] = {0u, 0u, 0u, 0u};
    for (int j = 0; j < 16; j++) {
        unsigned int b = enc_e4m3(src[o * K + k16 * 16 + j]);
        w[j >> 2] |= b << (8 * (j & 3));
    }
    size_t base = ((size_t)k16 * LDP + off + o) * 4;
    dst[base + 0] = w[0]; dst[base + 1] = w[1];
    dst[base + 2] = w[2]; dst[base + 3] = w[3];
}

__global__ void pack_bias3(const float* __restrict__ s0, int n0,
                           const float* __restrict__ s1, int n1,
                           const float* __restrict__ s2, int n2,
                           float* __restrict__ dst)
{
    int i = blockIdx.x * blockDim.x + threadIdx.x;
    if (i < n0) dst[i] = s0[i];
    else if (i < n0 + n1) dst[i] = s1[i - n0];
    else if (i < n0 + n1 + n2) dst[i] = s2[i - n0 - n1];
}

// ---------------------------------------------------------------------------
__device__ __forceinline__ float dot2(uint32 w, uint32 x, float acc)
{
#if __has_builtin(__builtin_amdgcn_fdot2)
    return __builtin_amdgcn_fdot2(__builtin_bit_cast(h2_t, w),
                                  __builtin_bit_cast(h2_t, x), acc, false);
#else
    h2_t a = __builtin_bit_cast(h2_t, w), b = __builtin_bit_cast(h2_t, x);
    return acc + (float)a[0] * (float)b[0] + (float)a[1] * (float)b[1];
#endif
}

__device__ __forceinline__ float dot8(uint4 w, uint4 x, float acc)
{
    acc = dot2(w.x, x.x, acc);
    acc = dot2(w.y, x.y, acc);
    acc = dot2(w.z, x.z, acc);
    acc = dot2(w.w, x.w, acc);
    return acc;
}

// 4 fp8 (one uint32) against de-interleaved packed-fp16 x pairs.
// e4m3 -> fp16 exact: ((b&0x80)<<8)|((b&0x7f)<<7) == true_value * 2^-8
// (x is pre-scaled by 256 at LDS-pack time, so products are exact-scale).
__device__ __forceinline__ float dot4_fp8(uint32 wq, uint32 xe, uint32 xo, float acc)
{
    uint32 ev = wq & 0x00ff00ffu;
    uint32 od = (wq >> 8) & 0x00ff00ffu;
    uint32 pe = ((ev & 0x00800080u) << 8) | ((ev & 0x007f007fu) << 7);
    uint32 po = ((od & 0x00800080u) << 8) | ((od & 0x007f007fu) << 7);
    acc = dot2(pe, xe, acc);
    acc = dot2(po, xo, acc);
    return acc;
}

// 16 fp8 weights (uint4) vs 8 packed x pairs (de-interleaved): xp[2q]=(x0,x2), xp[2q+1]=(x1,x3)
__device__ __forceinline__ float dot16_fp8(uint4 w, const uint32* __restrict__ xp,
                                           float acc)
{
    acc = dot4_fp8(w.x, xp[0], xp[1], acc);
    acc = dot4_fp8(w.y, xp[2], xp[3], acc);
    acc = dot4_fp8(w.z, xp[4], xp[5], acc);
    acc = dot4_fp8(w.w, xp[6], xp[7], acc);
    return acc;
}

__device__ __forceinline__ void tri_decode(int p, int& l, int& i)
{
    int lo = (int)((sqrtf(8.f * (float)p + 1.f) - 1.f) * 0.5f);
    while ((lo + 1) * (lo + 2) / 2 <= p) lo++;
    while (lo * (lo + 1) / 2 > p) lo--;
    l = lo;
    i = p - lo * (lo + 1) / 2;
}

__device__ __forceinline__ float sigm_scaled(float z)
{
    return MINV + (MAXV - MINV) / (1.f + expf(-z));
}

__device__ __forceinline__ unsigned short f2h(float v)
{
    _Float16 h = (_Float16)v;
    return __builtin_bit_cast(unsigned short, h);
}

// normal-order pack (adjacent pairs) — for fp16 W1 consumers
__device__ __forceinline__ void pack1_to(int tid, float v, uint32* d)
{
    unsigned short us = f2h(v);
    int pi = __shfl_xor((int)us, 1);
    if ((tid & 1) == 0)
        d[tid >> 1] = (uint32)us | ((uint32)pi << 16);
}

// de-interleaved pack for fp8 consumers: per quad q, d[2q]=(x4q,x4q+2), d[2q+1]=(x4q+1,x4q+3)
__device__ __forceinline__ void pack_de(int tid, float v, uint32* d)
{
    unsigned short us = f2h(v);
    int pi = __shfl_xor((int)us, 2);
    if ((tid & 2) == 0)
        d[((tid >> 2) << 1) | (tid & 1)] = (uint32)us | ((uint32)pi << 16);
}

// ---------------------------------------------------------------------------
// R7 skeleton (3.65ms verified): 1 elem/block, 1024 threads, 4 waves/SIMD.
// fp8-e4m3 weight streams (W2/head1/head2) with branch-free shift decode
// feeding the same v_dot2 pipeline; W1 fp16 staged in LDS.
__global__ __launch_bounds__(1024, 4) void kf_kernel(
    const float* __restrict__ u, const float* __restrict__ a,
    const uint32* __restrict__ wsu,
    const float* __restrict__ b1, const float* __restrict__ b2,
    const float* __restrict__ alpha_p,
    float* __restrict__ out)
{
    const int tid = threadIdx.x;
    const int b   = blockIdx.x;
    const float alpha = alpha_p[0];

    const uint4* W1h  = (const uint4*)(wsu + OFF_W1);
    const uint4* W2f8 = (const uint4*)(wsu + OFF_W2F8);
    const uint4* H1f8 = (const uint4*)(wsu + OFF_H1F8);
    const uint4* H2f8 = (const uint4*)(wsu + OFF_H2F8);
    const float* BH1  = (const float*)(wsu + OFF_B1);
    const float* BH2  = (const float*)(wsu + OFF_B2);

    __shared__ alignas(16) uint4  s_W1[4 * NH];      // 16 KB
    __shared__ alignas(16) uint32 s_h1x[NH / 2];     // de-interleaved, x*256
    __shared__ alignas(16) uint32 s_h2x[NH / 2];     // de-interleaved, x*256
    __shared__ alignas(16) uint32 s_qmh[NX / 2];     // normal order (W1)
    __shared__ alignas(16) uint32 s_pmh[NX / 2];
    __shared__ float s_part[4][NH];
    __shared__ float s_Am[NX * NXP];
    __shared__ float s_Bm[NX * NU];
    __shared__ float s_nx[NX];
    __shared__ float s_C[NA * NXP];
    __shared__ float s_na[NA];
    __shared__ float s_qm[NX], s_qc[NX * NXP];
    __shared__ float s_pm[NX], s_pc[NX * NXP];
    __shared__ float s_T2[NX * NXP];
    __shared__ float s_T1[NA * NXP];
    __shared__ float s_S[NA * NA];
    __shared__ float s_Y[NA * NX];
    __shared__ float s_innov[NA];
    __shared__ float s_a[NA], s_u[NU];

    const size_t pmO = 0;
    const size_t pcO = (size_t)NT * NB * NX;
    const size_t qmO = pcO + (size_t)NT * NB * NX * NX;
    const size_t qcO = qmO + (size_t)NT * NB * NX;

    // Hoisted triangular index maps (constant over t)
    int iT = 0, lT = 0;
    if (tid < 528) tri_decode(tid, lT, iT);
    int iS = 0, lS = 0;
    if (tid < 300) tri_decode(tid, lS, iS);

    // Stage W1 into LDS (1024 uint4, one per lane)
    s_W1[tid] = W1h[tid];

    for (int t = 0; t < NT; ++t) {
        const size_t mIdx = (size_t)t * NB + b;

        if (t == 0) {
            if (tid < NX) s_pm[tid] = 0.f;
            if (tid < NX / 2) s_pmh[tid] = 0u;
            {
                int i = tid >> 5, l = tid & 31;
                s_pc[i * NXP + l] = (i == l) ? 1.f : 0.f;
            }
            __syncthreads();
        } else {
            // ===== A1: lanes<256: W1@qm (LDS fp16) ; others: store qm/qc[t-1] =====
            if (tid < NH) {
                const uint4* xh = (const uint4*)s_qmh;
                float acc = b1[tid];
                #pragma unroll
                for (int k8 = 0; k8 < 4; k8++)
                    acc = dot8(s_W1[k8 * NH + tid], xh[k8], acc);
                pack_de(tid, fmaxf(acc, 0.f) * 256.f, s_h1x);
            } else {
                const size_t mPrev = (size_t)(t - 1) * NB + b;
                for (int s = tid - 256; s < NX + NX * NX; s += 768) {
                    if (s < NX)
                        __builtin_nontemporal_store(s_qm[s], out + qmO + mPrev * NX + s);
                    else {
                        int o = s - NX, i = o >> 5, l = o & 31;
                        __builtin_nontemporal_store(s_qc[i * NXP + l],
                                                    out + qcO + mPrev * NX * NX + o);
                    }
                }
                if (tid >= 1016)
                    s_u[tid - 1016] = u[((size_t)(t - 1) * NB + b) * NU + (tid - 1016)];
            }
            __syncthreads();

            // ===== A2: trunk-W2 fp8, split-K x4 =====
            {
                int o = tid & 255, g = tid >> 8;
                float acc = 0.f;
                #pragma unroll
                for (int r = 0; r < 4; r++) {
                    int k16 = g * 4 + r;
                    acc = dot16_fp8(W2f8[k16 * NH + o], s_h1x + k16 * 8, acc);
                }
                s_part[g][o] = acc;
            }
            __syncthreads();

            // ===== A3: h2 reduce + relu + pack (de-interleaved, x256) =====
            if (tid < NH) {
                float v = fmaxf(s_part[0][tid] + s_part[1][tid] +
                                s_part[2][tid] + s_part[3][tid] + b2[tid], 0.f);
                pack_de(tid, v * 256.f, s_h2x);
            }
            __syncthreads();

            // ===== A4: head1 fp8 (Am | Bm | nx) =====
            {
                int o0 = tid, o1 = tid + 1024;
                bool has1 = (o1 < H1O);
                float a0 = BH1[o0];
                float a1 = has1 ? BH1[o1] : 0.f;
                #pragma unroll 2
                for (int k16 = 0; k16 < 16; k16++) {
                    const uint32* xp = s_h2x + k16 * 8;
                    a0 = dot16_fp8(H1f8[k16 * H1P + o0], xp, a0);
                    if (has1) a1 = dot16_fp8(H1f8[k16 * H1P + o1], xp, a1);
                }
                {
                    int i = o0 >> 5, l = o0 & 31;
                    s_Am[i * NXP + l] = ((i == l) ? 1.f : 0.f) + alpha * a0;
                }
                if (has1) {
                    if (o1 < NX * NX + NX * NU) s_Bm[o1 - NX * NX] = a1;
                    else s_nx[o1 - (NX * NX + NX * NU)] = sigm_scaled(a1);
                }
            }
            __syncthreads();

            // ===== A5: T2 = Am@qc (1/lane) ; pm = Am@qm + Bm@u =====
            {
                int i = tid >> 5, l = tid & 31;
                float acc = 0.f;
                #pragma unroll
                for (int j = 0; j < NX; j++)
                    acc = fmaf(s_Am[i * NXP + j], s_qc[j * NXP + l], acc);
                s_T2[i * NXP + l] = acc;
            }
            if (tid < NX) {
                float acc = 0.f;
                #pragma unroll
                for (int j = 0; j < NX; j++) acc = fmaf(s_Am[tid * NXP + j], s_qm[j], acc);
                #pragma unroll
                for (int j = 0; j < NU; j++) acc = fmaf(s_Bm[tid * NU + j], s_u[j], acc);
                s_pm[tid] = acc;
                pack1_to(tid, acc, s_pmh);
            }
            __syncthreads();

            // ===== A6: pc = psd(T2 @ Am^T + diag(nx)) — 1/lane =====
            if (tid < 528) {
                int i = iT, l = lT;
                float a_il = 0.f, a_li = 0.f;
                #pragma unroll
                for (int j = 0; j < NX; j++) {
                    a_il = fmaf(s_T2[i * NXP + j], s_Am[l * NXP + j], a_il);
                    a_li = fmaf(s_T2[l * NXP + j], s_Am[i * NXP + j], a_li);
                }
                if (i == l) {
                    s_pc[i * NXP + i] = a_il + s_nx[i] + EPSV;
                } else {
                    float v = 0.5f * (a_il + a_li);
                    s_pc[i * NXP + l] = v;
                    s_pc[l * NXP + i] = v;
                }
            }
            __syncthreads();
        }

        // ===== B1: lanes<256: W1@pm (LDS fp16) ; others: store pm/pc[t] =====
        if (tid < NH) {
            const uint4* xh = (const uint4*)s_pmh;
            float acc = b1[tid];
            #pragma unroll
            for (int k8 = 0; k8 < 4; k8++)
                acc = dot8(s_W1[k8 * NH + tid], xh[k8], acc);
            pack_de(tid, fmaxf(acc, 0.f) * 256.f, s_h1x);
        } else {
            for (int s = tid - 256; s < NX + NX * NX; s += 768) {
                if (s < NX)
                    __builtin_nontemporal_store(s_pm[s], out + pmO + mIdx * NX + s);
                else {
                    int o = s - NX, i = o >> 5, l = o & 31;
                    __builtin_nontemporal_store(s_pc[i * NXP + l],
                                                out + pcO + mIdx * NX * NX + o);
                }
            }
            if (tid >= 1000)
                s_a[tid - 1000] = a[mIdx * NA + (tid - 1000)];
        }
        __syncthreads();

        // ===== B2: trunk-W2 fp8, split-K x4 =====
        {
            int o = tid & 255, g = tid >> 8;
            float acc = 0.f;
            #pragma unroll
            for (int r = 0; r < 4; r++) {
                int k16 = g * 4 + r;
                acc = dot16_fp8(W2f8[k16 * NH + o], s_h1x + k16 * 8, acc);
            }
            s_part[g][o] = acc;
        }
        __syncthreads();

        // ===== B3: h2 reduce + relu + pack =====
        if (tid < NH) {
            float v = fmaxf(s_part[0][tid] + s_part[1][tid] +
                            s_part[2][tid] + s_part[3][tid] + b2[tid], 0.f);
            pack_de(tid, v * 256.f, s_h2x);
        }
        __syncthreads();

        // ===== B4: head2 fp8 (C | na), 1/lane =====
        if (tid < H2P) {
            float acc = BH2[tid];
            #pragma unroll 4
            for (int k16 = 0; k16 < 16; k16++)
                acc = dot16_fp8(H2f8[k16 * H2P + tid], s_h2x + k16 * 8, acc);
            if (tid < NA * NX) {
                int i = tid >> 5, l = tid & 31;
                s_C[i * NXP + l] = acc;
            } else if (tid < H2O) {
                s_na[tid - NA * NX] = sigm_scaled(acc);
            }
        }
        __syncthreads();

        // ===== B5: T1 = C@pc (1/lane) ; innov = a - C@pm =====
        if (tid < NA * NX) {
            int i = tid >> 5, l = tid & 31;
            float acc = 0.f;
            #pragma unroll
            for (int k = 0; k < NX; k++)
                acc = fmaf(s_C[i * NXP + k], s_pc[k * NXP + l], acc);
            s_T1[i * NXP + l] = acc;
        }
        if (tid >= 1000) {
            int i = tid - 1000;
            float acc = s_a[i];
            #pragma unroll
            for (int j = 0; j < NX; j++)
                acc = fmaf(-s_C[i * NXP + j], s_pm[j], acc);
            s_innov[i] = acc;
        }
        __syncthreads();

        // ===== B6: S = T1 @ C^T + diag(na) — 1/lane =====
        if (tid < 300) {
            float acc = 0.f;
            #pragma unroll
            for (int j = 0; j < NX; j++)
                acc = fmaf(s_T1[iS * NXP + j], s_C[lS * NXP + j], acc);
            if (iS == lS) acc += s_na[iS];
            s_S[iS * NA + lS] = acc;
            s_S[lS * NA + iS] = acc;
        }
        __syncthreads();

        // ===== B7: single-wave register Gauss-Jordan: Y = S^-1 T1 =====
        if (tid < 64) {
            const int j = tid;
            float r[NA];
            #pragma unroll
            for (int i = 0; i < NA; i++) {
                float v = 0.f;
                if (j < NA) v = s_S[i * NA + j];
                else if (j < NA + NX) v = s_T1[i * NXP + (j - NA)];
                r[i] = v;
            }
            #pragma unroll
            for (int k = 0; k < NA; k++) {
                float piv = __shfl(r[k], k);
                float ip = 1.0f / piv;
                r[k] *= ip;
                #pragma unroll
                for (int i = 0; i < NA; i++) {
                    if (i == k) continue;
                    float f = __shfl(r[i], k);
                    r[i] = fmaf(-f, r[k], r[i]);
                }
            }
            if (j >= NA && j < NA + NX) {
                #pragma unroll
                for (int i = 0; i < NA; i++) s_Y[i * NX + (j - NA)] = r[i];
            }
        }
        __syncthreads();

        // ===== B8: qm = pm + Y^T innov ; qc = psd(pc - Y^T T1) — 1/lane =====
        if (tid < NX) {
            float acc = s_pm[tid];
            #pragma unroll
            for (int i = 0; i < NA; i++)
                acc = fmaf(s_Y[i * NX + tid], s_innov[i], acc);
            s_qm[tid] = acc;
            pack1_to(tid, acc, s_qmh);
        }
        if (tid < 528) {
            int i = iT, l = lT;
            float t_il = 0.f, t_li = 0.f;
            #pragma unroll
            for (int q = 0; q < NA; q++) {
                t_il = fmaf(s_Y[q * NX + i], s_T1[q * NXP + l], t_il);
                t_li = fmaf(s_Y[q * NX + l], s_T1[q * NXP + i], t_li);
            }
            if (i == l) {
                s_qc[i * NXP + i] = s_pc[i * NXP + i] - t_il + EPSV;
            } else {
                float v = 0.5f * ((s_pc[i * NXP + l] - t_il) + (s_pc[l * NXP + i] - t_li));
                s_qc[i * NXP + l] = v;
                s_qc[l * NXP + i] = v;
            }
        }
        __syncthreads();
    }

    // Epilogue: store final qm/qc (t = NT-1), coalesced
    {
        const size_t mLast = (size_t)(NT - 1) * NB + b;
        for (int s = tid; s < NX + NX * NX; s += 1024) {
            if (s < NX)
                __builtin_nontemporal_store(s_qm[s], out + qmO + mLast * NX + s);
            else {
                int o = s - NX, i = o >> 5, l = o & 31;
                __builtin_nontemporal_store(s_qc[i * NXP + l],
                                            out + qcO + mLast * NX * NX + o);
            }
        }
    }
}

// ---------------------------------------------------------------------------
extern "C" void kernel_launch(void* const* d_in, const int* in_sizes, int n_in,
                              void* d_out, int out_size, void* d_ws, size_t ws_size,
                              hipStream_t stream)
{
    const float* u    = (const float*)d_in[0];
    const float* a    = (const float*)d_in[1];
    const float* W1   = (const float*)d_in[2];
    const float* b1   = (const float*)d_in[3];
    const float* W2   = (const float*)d_in[4];
    const float* b2   = (const float*)d_in[5];
    const float* WA   = (const float*)d_in[6];
    const float* bA   = (const float*)d_in[7];
    const float* WB   = (const float*)d_in[8];
    const float* bB   = (const float*)d_in[9];
    const float* WC   = (const float*)d_in[10];
    const float* bC   = (const float*)d_in[11];
    const float* Wnx  = (const float*)d_in[12];
    const float* bnx  = (const float*)d_in[13];
    const float* Wna  = (const float*)d_in[14];
    const float* bna  = (const float*)d_in[15];
    const float* alph = (const float*)d_in[16];

    uint32* wsu = (uint32*)d_ws;
    float* out = (float*)d_out;

    // W1 stays fp16 (staged to LDS in-kernel)
    {
        int n = NH * (NX / 2);
        pack_half_off<<<(n + 255) / 256, 256, 0, stream>>>(W1, wsu + OFF_W1, NH, NX, NH, 0);
    }
    // fp8 packs
    auto pk8 = [&](const float* src, int O, int K, size_t dst_off, int LDP, int off) {
        int n = O * (K / 16);
        pack_fp8_off<<<(n + 255) / 256, 256, 0, stream>>>(src, wsu + dst_off, O, K, LDP, off);
    };
    pk8(W2,  NH,      NH, OFF_W2F8, NH,  0);
    pk8(WA,  NX * NX, NH, OFF_H1F8, H1P, 0);
    pk8(WB,  NX * NU, NH, OFF_H1F8, H1P, NX * NX);
    pk8(Wnx, NX,      NH, OFF_H1F8, H1P, NX * NX + NX * NU);
    pk8(WC,  NA * NX, NH, OFF_H2F8, H2P, 0);
    pk8(Wna, NA,      NH, OFF_H2F8, H2P, NA * NX);

    pack_bias3<<<(H1O + 255) / 256, 256, 0, stream>>>(bA, NX * NX, bB, NX * NU, bnx, NX,
                                                      (float*)(wsu + OFF_B1));
    pack_bias3<<<(H2O + 255) / 256, 256, 0, stream>>>(bC, NA * NX, bna, NA, nullptr, 0,
                                                      (float*)(wsu + OFF_B2));

    kf_kernel<<<NB, 1024, 0, stream>>>(u, a, wsu, b1, b2, alph, out);
}